// Round 4
// baseline (387.630 us; speedup 1.0000x reference)
//
#include <hip/hip_runtime.h>
#include <math.h>

#define BB 256
#define DD 4096
#define MAXR 31
#define NCAND 4
#define CAP 512
// filter: u < U_THRESH  =>  g(u) < 3.8 (incl. fp32 rounding slop). GUARD=4.0 check.
#define U_THRESH 0.9778f
#define GUARD 4.0f

typedef float f32x4 __attribute__((ext_vector_type(4)));
typedef short bf16x8 __attribute__((ext_vector_type(8)));

// ---------------- threefry2x32 (JAX schedule) ----------------
__device__ __forceinline__ void tf2x32(unsigned k0, unsigned k1, unsigned c0, unsigned c1,
                                       unsigned &o0, unsigned &o1) {
  unsigned ks2 = k0 ^ k1 ^ 0x1BD11BDAu;
  unsigned x0 = c0 + k0;
  unsigned x1 = c1 + k1;
#define TF_ROT(v, r) (((v) << (r)) | ((v) >> (32 - (r))))
#define TF_R(r) { x0 += x1; x1 = TF_ROT(x1, r); x1 ^= x0; }
  TF_R(13) TF_R(15) TF_R(26) TF_R(6)   x0 += k1;  x1 += ks2 + 1u;
  TF_R(17) TF_R(29) TF_R(16) TF_R(24)  x0 += ks2; x1 += k0 + 2u;
  TF_R(13) TF_R(15) TF_R(26) TF_R(6)   x0 += k0;  x1 += k1 + 3u;
  TF_R(17) TF_R(29) TF_R(16) TF_R(24)  x0 += k1;  x1 += ks2 + 4u;
  TF_R(13) TF_R(15) TF_R(26) TF_R(6)   x0 += ks2; x1 += k0 + 5u;
#undef TF_R
#undef TF_ROT
  o0 = x0; o1 = x1;
}

__device__ __forceinline__ unsigned tf_xor(unsigned k0, unsigned k1, unsigned c0, unsigned c1) {
  unsigned a, b; tf2x32(k0, k1, c0, c1, a, b); return a ^ b;
}

__device__ __forceinline__ float bits_to_unit(unsigned bits) {
  return __uint_as_float(0x3f800000u | (bits >> 9)) - 1.0f;
}

// ---------------- bf16 helpers (RNE) ----------------
__device__ __forceinline__ unsigned short rne_bf16(float f) {
  unsigned u = __float_as_uint(f);
  u += 0x7FFFu + ((u >> 16) & 1u);
  return (unsigned short)(u >> 16);
}
__device__ __forceinline__ float bf16_to_f(unsigned short h) {
  return __uint_as_float(((unsigned)h) << 16);
}

// ---------------- fast accurate double log (~1e-13 rel) ----------------
__device__ __forceinline__ double dlog(double x) {
  unsigned long long ub = (unsigned long long)__double_as_longlong(x);
  int e = (int)((ub >> 52) & 0x7FFull) - 1022;
  double m = __longlong_as_double((long long)((ub & 0x000FFFFFFFFFFFFFull) | 0x3FE0000000000000ull));
  if (m < 0.70710678118654752440) { m *= 2.0; e -= 1; }
  double r = (m - 1.0) / (m + 1.0);
  double z = r * r;
  double s = fma(z, fma(z, fma(z, fma(z, fma(z, fma(z, 1.0/15.0, 1.0/13.0),
                1.0/11.0), 1.0/9.0), 1.0/7.0), 1.0/5.0), 1.0/3.0);
  double t2 = 2.0 * r;
  return fma((double)e, 0.69314718055994530942, fma(t2 * z, s, t2));
}

__device__ __forceinline__ float gumbel_from_u(float f) {
  float uu = (f == 0.0f) ? 1.17549435e-38f : f;
  float t1 = (float)dlog((double)uu);
  return -(float)dlog((double)(-t1));
}

__device__ __forceinline__ float gumbel_of(unsigned kk0, unsigned kk1, unsigned n) {
  return gumbel_from_u(bits_to_unit(tf_xor(kk0, kk1, 0u, n)));
}

__device__ __forceinline__ double blockReduce256(double v, double* lds) {
  #pragma unroll
  for (int off = 32; off > 0; off >>= 1) v += __shfl_down(v, off);
  __syncthreads();
  if ((threadIdx.x & 63) == 0) lds[threadIdx.x >> 6] = v;
  __syncthreads();
  return lds[0] + lds[1] + lds[2] + lds[3];
}

// ---------------- K0: all small RNG draws ----------------
__global__ void k_rng(unsigned* __restrict__ keys_out, int* __restrict__ radius,
                      float* __restrict__ u_acc) {
  int t = threadIdx.x;
  unsigned krad0, krad1, ksamp0, ksamp1, kacc0, kacc1;
  tf2x32(0u, 42u, 0u, 0u, krad0, krad1);
  tf2x32(0u, 42u, 0u, 1u, ksamp0, ksamp1);
  tf2x32(0u, 42u, 0u, 2u, kacc0, kacc1);
  if (t < MAXR) {
    unsigned a, c;
    tf2x32(ksamp0, ksamp1, 0u, (unsigned)t, a, c);
    keys_out[2*t] = a; keys_out[2*t+1] = c;
  }
  unsigned k10, k11, k20, k21;
  tf2x32(krad0, krad1, 0u, 0u, k10, k11);
  tf2x32(krad0, krad1, 0u, 1u, k20, k21);
  unsigned hi = tf_xor(k10, k11, 0u, (unsigned)t);
  unsigned lo = tf_xor(k20, k21, 0u, (unsigned)t);
  unsigned off = ((hi % 31u) * 4u + (lo % 31u)) % 31u;
  radius[t] = 1 + (int)off;
  unsigned ab = tf_xor(kacc0, kacc1, 0u, (unsigned)t);
  u_acc[t] = bits_to_unit(ab);
}

// ---------------- K1a: x fp32 -> bf16 (exact: x is 0/1) ----------------
__global__ void k_xcvt(const float* __restrict__ x, unsigned short* __restrict__ xb) {
  int i = (blockIdx.x * 256 + threadIdx.x) * 8;
  float4 a = *(const float4*)&x[i];
  float4 b = *(const float4*)&x[i + 4];
  union { unsigned short u[8]; int4 v; } pk;
  pk.u[0] = rne_bf16(a.x); pk.u[1] = rne_bf16(a.y);
  pk.u[2] = rne_bf16(a.z); pk.u[3] = rne_bf16(a.w);
  pk.u[4] = rne_bf16(b.x); pk.u[5] = rne_bf16(b.y);
  pk.u[6] = rne_bf16(b.z); pk.u[7] = rne_bf16(b.w);
  *(int4*)&xb[i] = pk.v;
}

// ---------------- K1b: MFMA 3-limb bf16 GEMM: Cpart[kc] = W(64rows) * x^T ----------------
// computes grad^T tile [64 x 256]; W symmetric so grad^T = W * x^T.
// A = W rows (fp32 -> 3 bf16 limbs in-register, Dekker-exact), B = x bf16 (exact).
__global__ __launch_bounds__(256) void k_gemm_mfma(const unsigned short* __restrict__ xb,
                                                   const float* __restrict__ W,
                                                   float* __restrict__ Cpart, int klen) {
  int mt = blockIdx.x, kc = blockIdx.y;
  int t = threadIdx.x;
  int wave = t >> 6, lane = t & 63;
  int quad = lane >> 4, lr = lane & 15;
  int m0 = mt * 64 + wave * 16;
  const float* wrow = W + (size_t)(m0 + lr) * DD;   // A: lane's W row
  int kstart = kc * klen;
  int nsteps = klen / 32;

  f32x4 acc[16];
  #pragma unroll
  for (int ct = 0; ct < 16; ct++) acc[ct] = (f32x4){0.f, 0.f, 0.f, 0.f};

  int kb0 = kstart + quad * 8;
  float4 wa = *(const float4*)&wrow[kb0];
  float4 wb = *(const float4*)&wrow[kb0 + 4];

  for (int ks = 0; ks < nsteps; ks++) {
    int kb = kstart + ks * 32 + quad * 8;
    // prefetch next W chunk (HBM latency cover)
    int ksn = (ks + 1 < nsteps) ? ks + 1 : ks;
    int kbn = kstart + ksn * 32 + quad * 8;
    float4 na = *(const float4*)&wrow[kbn];
    float4 nb = *(const float4*)&wrow[kbn + 4];

    // 3-limb Dekker split of 8 W values (residuals exact in fp32)
    bf16x8 hi, mi, lo;
    float wf[8] = {wa.x, wa.y, wa.z, wa.w, wb.x, wb.y, wb.z, wb.w};
    #pragma unroll
    for (int i2 = 0; i2 < 8; i2++) {
      unsigned short h = rne_bf16(wf[i2]);
      float r1 = wf[i2] - bf16_to_f(h);
      unsigned short m = rne_bf16(r1);
      float r2 = r1 - bf16_to_f(m);
      unsigned short l = rne_bf16(r2);
      hi[i2] = (short)h; mi[i2] = (short)m; lo[i2] = (short)l;
    }
    // B frags: x bf16, K-contiguous 16B loads (L1/L2-resident)
    bf16x8 bfr[16];
    #pragma unroll
    for (int ct = 0; ct < 16; ct++) {
      const unsigned short* bp = xb + (size_t)(ct * 16 + lr) * DD + kb;
      bfr[ct] = *(const bf16x8*)bp;
    }
    #pragma unroll
    for (int ct = 0; ct < 16; ct++) {
      acc[ct] = __builtin_amdgcn_mfma_f32_16x16x32_bf16(lo, bfr[ct], acc[ct], 0, 0, 0);
      acc[ct] = __builtin_amdgcn_mfma_f32_16x16x32_bf16(mi, bfr[ct], acc[ct], 0, 0, 0);
      acc[ct] = __builtin_amdgcn_mfma_f32_16x16x32_bf16(hi, bfr[ct], acc[ct], 0, 0, 0);
    }
    wa = na; wb = nb;
  }
  // store: D row=(quad*4+r) -> m, col=lr -> batch b   (C/D: col=lane&15, row=quad*4+reg)
  float* Cp = Cpart + (size_t)kc * DD * BB;
  #pragma unroll
  for (int ct = 0; ct < 16; ct++) {
    #pragma unroll
    for (int r = 0; r < 4; r++) {
      int m = m0 + quad * 4 + r;
      int b = ct * 16 + lr;
      Cp[(size_t)m * BB + b] = acc[ct][r];
    }
  }
}

// ---------------- K1c: transposing split-K reduce + bias -> grad[b][d], sc_x ----------------
__global__ __launch_bounds__(256) void k_reduce(const float* __restrict__ Cpart,
                                                const float* __restrict__ bias,
                                                const float* __restrict__ x,
                                                float* __restrict__ grad,
                                                float* __restrict__ sc, int KC) {
  __shared__ float tile[64][65];
  int d0 = blockIdx.x * 64, b0 = blockIdx.y * 64;
  int t = threadIdx.x;
  int j = t & 63, i0 = t >> 6;
  #pragma unroll
  for (int ii = 0; ii < 16; ii++) {
    int i = i0 + 4 * ii;
    float s = 0.f;
    for (int kc = 0; kc < KC; kc++)
      s += Cpart[(size_t)kc * DD * BB + (size_t)(d0 + i) * BB + (b0 + j)];
    tile[i][j] = s + bias[d0 + i];
  }
  __syncthreads();
  #pragma unroll
  for (int ii = 0; ii < 16; ii++) {
    int bloc = i0 + 4 * ii;
    int dloc = j;
    float g = tile[dloc][bloc];
    size_t o = (size_t)(b0 + bloc) * DD + d0 + dloc;
    grad[o] = g;
    float xv = x[o];
    sc[o] = (1.0f - 2.0f * xv) * g * 0.5f;
  }
}

// ---------------- K2: score_x + per-row max of sc_x ----------------
__global__ __launch_bounds__(256) void k_score(const float* __restrict__ x, const float* __restrict__ grad,
                                               const float* __restrict__ bias, double* __restrict__ score,
                                               float* __restrict__ scmax) {
  int b = blockIdx.x, t = threadIdx.x;
  double s1 = 0.0, s2 = 0.0;
  float mx = -INFINITY;
  for (int k = 0; k < 16; k++) {
    int d = t + 256*k; size_t o = (size_t)b*DD + d;
    float xvf = x[o];
    float gv = grad[o];
    float scv = (1.0f - 2.0f*xvf) * gv * 0.5f;  // identical rounding to k_reduce
    mx = fmaxf(mx, scv);
    double xv = xvf;
    s1 += xv * (double)gv;
    s2 += xv * (double)bias[d];
  }
  __shared__ double lds[4];
  double S1 = blockReduce256(s1, lds);
  double S2 = blockReduce256(s2, lds);
  #pragma unroll
  for (int off = 32; off > 0; off >>= 1) mx = fmaxf(mx, __shfl_down(mx, off));
  __shared__ float lmx[4];
  __syncthreads();
  if ((t & 63) == 0) lmx[t >> 6] = mx;
  __syncthreads();
  if (t == 0) {
    score[b] = 0.5 * (S1 + S2);
    scmax[b] = fmaxf(fmaxf(lmx[0], lmx[1]), fmaxf(lmx[2], lmx[3]));
  }
}

// ---------------- K4: per (row,step) top-4 via u-filter + exact fallback ----------------
__global__ __launch_bounds__(256) void k_cand(const float* __restrict__ sc_x,
                                              const unsigned* __restrict__ keys,
                                              const float* __restrict__ scmax,
                                              int* __restrict__ cand_i) {
  int blk = blockIdx.x;
  int b = blk / MAXR, j = blk % MAXR;
  unsigned kk0 = keys[2*j], kk1 = keys[2*j+1];
  int t = threadIdx.x;
  unsigned base = (unsigned)(b * DD);

  __shared__ int cnt;
  __shared__ int   lidx[CAP];
  __shared__ float lu[CAP];
  __shared__ float win_v_s;
  __shared__ int   win_i_s;
  __shared__ float ls_v[4];
  __shared__ int   ls_i[4];
  if (t == 0) cnt = 0;
  __syncthreads();

  // phase 1: threefry + uniform + cheap filter (the 97.8% fast path)
  #pragma unroll
  for (int p = 0; p < 16; p++) {
    int d = t + 256*p;
    unsigned bits = tf_xor(kk0, kk1, 0u, base + (unsigned)d);
    float f = bits_to_unit(bits);
    if (f >= U_THRESH) {
      int pos = atomicAdd(&cnt, 1);
      if (pos < CAP) { lidx[pos] = d; lu[pos] = f; }
    }
  }
  __syncthreads();
  int n = cnt;
  bool need_fallback = (n > CAP) || (n < NCAND);

  if (!need_fallback) {
    // phase 2: exact gumbel + top-4 over <=512 candidates (2 per thread)
    float v[2]; int di[2]; unsigned alive = 0u;
    #pragma unroll
    for (int q = 0; q < 2; q++) {
      int idx = t + 256*q;
      if (idx < n) {
        int d = lidx[idx];
        v[q] = sc_x[(size_t)b*DD + d] + gumbel_from_u(lu[idx]);
        di[q] = d;
        alive |= (1u << q);
      } else { v[q] = -INFINITY; di[q] = 0x7FFFFFFF; }
    }
    float v4 = -INFINITY;
    for (int r = 0; r < NCAND; r++) {
      float bv = -INFINITY; int bi = 0x7FFFFFFF;
      #pragma unroll
      for (int q = 0; q < 2; q++)
        if (((alive >> q) & 1u) && (v[q] > bv || (v[q] == bv && di[q] < bi))) { bv = v[q]; bi = di[q]; }
      #pragma unroll
      for (int off = 32; off > 0; off >>= 1) {
        float ov = __shfl_down(bv, off);
        int   oi = __shfl_down(bi, off);
        if (ov > bv || (ov == bv && oi < bi)) { bv = ov; bi = oi; }
      }
      if ((t & 63) == 0) { ls_v[t >> 6] = bv; ls_i[t >> 6] = bi; }
      __syncthreads();
      if (t == 0) {
        float fv = ls_v[0]; int fi = ls_i[0];
        #pragma unroll
        for (int w = 1; w < 4; w++)
          if (ls_v[w] > fv || (ls_v[w] == fv && ls_i[w] < fi)) { fv = ls_v[w]; fi = ls_i[w]; }
        win_v_s = fv; win_i_s = fi;
        cand_i[(size_t)blk * NCAND + r] = fi;
      }
      __syncthreads();
      int wd = win_i_s;
      v4 = win_v_s;
      #pragma unroll
      for (int q = 0; q < 2; q++) if (di[q] == wd) alive &= ~(1u << q);
    }
    // guarantee: every skipped element has v < scmax + 3.8 < scmax + GUARD
    if (v4 >= scmax[b] + GUARD) return;
    need_fallback = true;
    __syncthreads();
  }

  // fallback: full exact computation (statistically ~never; preserves exactness)
  {
    float v[16];
    #pragma unroll
    for (int p = 0; p < 16; p++) {
      int d = t + 256*p;
      v[p] = sc_x[(size_t)b*DD + d] + gumbel_of(kk0, kk1, base + (unsigned)d);
    }
    unsigned alive = 0xFFFFu;
    float lv = -INFINITY; int li = 0x7FFFFFFF;
    #pragma unroll
    for (int p = 0; p < 16; p++)
      if (v[p] > lv) { lv = v[p]; li = t + 256*p; }
    for (int r = 0; r < NCAND; r++) {
      float bv = lv; int bi = li;
      #pragma unroll
      for (int off = 32; off > 0; off >>= 1) {
        float ov = __shfl_down(bv, off);
        int   oi = __shfl_down(bi, off);
        if (ov > bv || (ov == bv && oi < bi)) { bv = ov; bi = oi; }
      }
      if ((t & 63) == 0) { ls_v[t >> 6] = bv; ls_i[t >> 6] = bi; }
      __syncthreads();
      if (t == 0) {
        float fv = ls_v[0]; int fi = ls_i[0];
        #pragma unroll
        for (int w = 1; w < 4; w++)
          if (ls_v[w] > fv || (ls_v[w] == fv && ls_i[w] < fi)) { fv = ls_v[w]; fi = ls_i[w]; }
        win_i_s = fi;
        cand_i[(size_t)blk * NCAND + r] = fi;
      }
      __syncthreads();
      if (r < NCAND - 1) {
        int wi = win_i_s;
        if (t == (wi & 255)) {
          alive &= ~(1u << (wi >> 8));
          lv = -INFINITY; li = 0x7FFFFFFF;
          #pragma unroll
          for (int p = 0; p < 16; p++)
            if (((alive >> p) & 1u) && v[p] > lv) { lv = v[p]; li = t + 256*p; }
        }
      }
    }
  }
}

// ---------------- K5: per-row blocked-chain resolution w/ exact fallback ----------------
__global__ __launch_bounds__(256) void k_select(const int* __restrict__ cand_i,
                                                const float* __restrict__ sc_x,
                                                const unsigned* __restrict__ keys,
                                                int* __restrict__ idx_all) {
  int b = blockIdx.x, t = threadIdx.x;
  __shared__ unsigned mask[128];
  __shared__ int pick_s;
  __shared__ float ls_v[4];
  __shared__ int   ls_i[4];
  if (t < 128) mask[t] = 0u;
  __syncthreads();
  for (int j = 0; j < MAXR; j++) {
    if (t == 0) {
      const int* ci = &cand_i[(size_t)(b*MAXR + j) * NCAND];
      int pick = -1;
      #pragma unroll
      for (int r = 0; r < NCAND; r++) {
        int idx = ci[r];
        if (pick < 0 && !((mask[idx >> 5] >> (idx & 31)) & 1u)) pick = idx;
      }
      pick_s = pick;
    }
    __syncthreads();
    if (pick_s < 0) {
      unsigned kk0 = keys[2*j], kk1 = keys[2*j+1];
      float lv = -INFINITY; int li = 0x7FFFFFFF;
      for (int p = 0; p < 16; p++) {
        int d = t + 256*p;
        if ((mask[d >> 5] >> (d & 31)) & 1u) continue;
        float vv = sc_x[(size_t)b*DD + d] + gumbel_of(kk0, kk1, (unsigned)(b*DD + d));
        if (vv > lv || (vv == lv && d < li)) { lv = vv; li = d; }
      }
      float bv = lv; int bi = li;
      #pragma unroll
      for (int off = 32; off > 0; off >>= 1) {
        float ov = __shfl_down(bv, off);
        int   oi = __shfl_down(bi, off);
        if (ov > bv || (ov == bv && oi < bi)) { bv = ov; bi = oi; }
      }
      if ((t & 63) == 0) { ls_v[t >> 6] = bv; ls_i[t >> 6] = bi; }
      __syncthreads();
      if (t == 0) {
        float fv = ls_v[0]; int fi = ls_i[0];
        #pragma unroll
        for (int w = 1; w < 4; w++)
          if (ls_v[w] > fv || (ls_v[w] == fv && ls_i[w] < fi)) { fv = ls_v[w]; fi = ls_i[w]; }
        pick_s = fi;
      }
      __syncthreads();
    }
    if (t == 0) {
      int pk = pick_s;
      idx_all[b*MAXR + j] = pk;
      mask[pk >> 5] |= (1u << (pk & 31));
    }
    __syncthreads();
  }
}

// ---------------- K6: y, grad_y (incremental), sc_y, score_y ----------------
__global__ __launch_bounds__(256) void k_y(const float* __restrict__ x, const float* __restrict__ W,
    const float* __restrict__ bias, const float* __restrict__ grad_x,
    const int* __restrict__ idx_all, const int* __restrict__ radius,
    float* __restrict__ yv, float* __restrict__ sc_y, double* __restrict__ score_y) {
  int b = blockIdx.x, t = threadIdx.x;
  __shared__ int   fidx[MAXR];
  __shared__ float fsgn[MAXR];
  int nf = radius[b];
  if (t < nf) {
    int id = idx_all[b*MAXR + t];
    fidx[t] = id;
    fsgn[t] = 1.0f - 2.0f * x[(size_t)b*DD + id];
  }
  __syncthreads();
  double s1 = 0.0, s2 = 0.0;
  for (int k = 0; k < 16; k++) {
    int d = t + 256*k;
    size_t o = (size_t)b*DD + d;
    float g = grad_x[o];
    float xval = x[o];
    float yval = xval;
    for (int jj = 0; jj < nf; jj++) {
      g = fmaf(fsgn[jj], W[(size_t)fidx[jj]*DD + d], g);
      if (fidx[jj] == d) yval = 1.0f - xval;
    }
    yv[o] = yval;
    sc_y[o] = (1.0f - 2.0f*yval) * g * 0.5f;
    s1 += (double)yval * (double)g;
    s2 += (double)yval * (double)bias[d];
  }
  __shared__ double lds[4];
  double S1 = blockReduce256(s1, lds);
  double S2 = blockReduce256(s2, lds);
  if (t == 0) score_y[b] = 0.5 * (S1 + S2);
}

// ---------------- K7: masked log-softmax sums, accept, output ----------------
__global__ __launch_bounds__(256) void k_accept(const float* __restrict__ x, const float* __restrict__ yv,
    const float* __restrict__ sc_x, const float* __restrict__ sc_y,
    const int* __restrict__ idx_all, const int* __restrict__ radius,
    const double* __restrict__ score_x, const double* __restrict__ score_y,
    const float* __restrict__ u_acc, float* __restrict__ out) {
  int b = blockIdx.x, t = threadIdx.x;
  double sx = 0.0, sy = 0.0;
  for (int k = 0; k < 16; k++) {
    int d = t + 256*k; size_t o = (size_t)b*DD + d;
    sx += exp((double)sc_x[o]);
    sy += exp((double)sc_y[o]);
  }
  __shared__ double lds[4];
  double S = blockReduce256(sx, lds);
  double T = blockReduce256(sy, lds);
  __shared__ float accf;
  if (t == 0) {
    int nf = radius[b];
    const int* ia = &idx_all[b*MAXR];
    double lf = 0.0, pre = 0.0;
    for (int jj = 0; jj < MAXR; jj++) {
      int id = ia[jj];
      double scv = (double)sc_x[(size_t)b*DD + id];
      if (jj < nf) lf += scv - dlog(S - pre);
      pre += exp(scv);
    }
    double lb = 0.0, suf = 0.0;
    for (int jj = MAXR-1; jj >= 0; jj--) {
      int id = ia[jj];
      double scv = (double)sc_y[(size_t)b*DD + id];
      if (jj < nf) lb += scv - dlog(T - suf);
      suf += exp(scv);
    }
    double log_acc = (lb + score_y[b]) - (lf + score_x[b]);
    accf = (exp(log_acc) >= (double)u_acc[b]) ? 1.0f : 0.0f;
  }
  __syncthreads();
  float a = accf;
  for (int k = 0; k < 16; k++) {
    int d = t + 256*k; size_t o = (size_t)b*DD + d;
    out[o] = a * yv[o] + (1.0f - a) * x[o];
  }
}

extern "C" void kernel_launch(void* const* d_in, const int* in_sizes, int n_in,
                              void* d_out, int out_size, void* d_ws, size_t ws_size,
                              hipStream_t stream) {
  const float* x    = (const float*)d_in[0];
  const float* W    = (const float*)d_in[1];
  const float* bias = (const float*)d_in[2];
  float* out = (float*)d_out;
  char* ws = (char*)d_ws;
  const size_t MB = 1ull << 20;

  float*          grad_x  = (float*)         (ws + 0*MB);
  float*          sc_x    = (float*)         (ws + 4*MB);
  float*          sc_y    = (float*)         (ws + 8*MB);
  float*          yv      = (float*)         (ws + 12*MB);
  unsigned short* xb      = (unsigned short*)(ws + 16*MB);
  int*            cand_i  = (int*)           (ws + 20*MB);
  int*            idx_all = (int*)           (ws + 21*MB);
  int*            radius  = (int*)           (ws + 21*MB + 64*1024);
  float*          u_acc   = (float*)         (ws + 21*MB + 68*1024);
  unsigned*       keys    = (unsigned*)      (ws + 21*MB + 72*1024);
  double*         score_x = (double*)        (ws + 21*MB + 80*1024);
  double*         score_y = (double*)        (ws + 21*MB + 96*1024);
  float*          scmax   = (float*)         (ws + 21*MB + 112*1024);
  float*          Cpart   = (float*)         (ws + 22*MB);

  size_t base = 22*MB;
  int KC = 1;
  if      (ws_size >= base + 32*MB) KC = 8;
  else if (ws_size >= base + 16*MB) KC = 4;
  else if (ws_size >= base +  8*MB) KC = 2;

  k_rng      <<<1, 256, 0, stream>>>(keys, radius, u_acc);
  k_xcvt     <<<512, 256, 0, stream>>>(x, xb);
  k_gemm_mfma<<<dim3(DD/64, KC), 256, 0, stream>>>(xb, W, Cpart, DD/KC);
  k_reduce   <<<dim3(DD/64, BB/64), 256, 0, stream>>>(Cpart, bias, x, grad_x, sc_x, KC);
  k_score    <<<BB, 256, 0, stream>>>(x, grad_x, bias, score_x, scmax);
  k_cand     <<<BB*MAXR, 256, 0, stream>>>(sc_x, keys, scmax, cand_i);
  k_select   <<<BB, 256, 0, stream>>>(cand_i, sc_x, keys, idx_all);
  k_y        <<<BB, 256, 0, stream>>>(x, W, bias, grad_x, idx_all, radius, yv, sc_y, score_y);
  k_accept   <<<BB, 256, 0, stream>>>(x, yv, sc_x, sc_y, idx_all, radius, score_x, score_y, u_acc, out);
}

// Round 5
// 376.561 us; speedup vs baseline: 1.0294x; 1.0294x over previous
//
#include <hip/hip_runtime.h>
#include <math.h>

#define BB 256
#define DD 4096
#define MAXR 31
#define NCAND 4
#define CAP 512
// filter: u < U_THRESH  =>  g(u) < 3.8 (incl. fp32 rounding slop). GUARD=4.0 check.
#define U_THRESH 0.9778f
#define GUARD 4.0f

typedef float f32x4 __attribute__((ext_vector_type(4)));
typedef short bf16x8 __attribute__((ext_vector_type(8)));

// ---------------- threefry2x32 (JAX schedule) ----------------
__device__ __forceinline__ void tf2x32(unsigned k0, unsigned k1, unsigned c0, unsigned c1,
                                       unsigned &o0, unsigned &o1) {
  unsigned ks2 = k0 ^ k1 ^ 0x1BD11BDAu;
  unsigned x0 = c0 + k0;
  unsigned x1 = c1 + k1;
#define TF_ROT(v, r) (((v) << (r)) | ((v) >> (32 - (r))))
#define TF_R(r) { x0 += x1; x1 = TF_ROT(x1, r); x1 ^= x0; }
  TF_R(13) TF_R(15) TF_R(26) TF_R(6)   x0 += k1;  x1 += ks2 + 1u;
  TF_R(17) TF_R(29) TF_R(16) TF_R(24)  x0 += ks2; x1 += k0 + 2u;
  TF_R(13) TF_R(15) TF_R(26) TF_R(6)   x0 += k0;  x1 += k1 + 3u;
  TF_R(17) TF_R(29) TF_R(16) TF_R(24)  x0 += k1;  x1 += ks2 + 4u;
  TF_R(13) TF_R(15) TF_R(26) TF_R(6)   x0 += ks2; x1 += k0 + 5u;
#undef TF_R
#undef TF_ROT
  o0 = x0; o1 = x1;
}

__device__ __forceinline__ unsigned tf_xor(unsigned k0, unsigned k1, unsigned c0, unsigned c1) {
  unsigned a, b; tf2x32(k0, k1, c0, c1, a, b); return a ^ b;
}

__device__ __forceinline__ float bits_to_unit(unsigned bits) {
  return __uint_as_float(0x3f800000u | (bits >> 9)) - 1.0f;
}

// ---------------- bf16 helpers (RNE) ----------------
__device__ __forceinline__ unsigned short rne_bf16(float f) {
  unsigned u = __float_as_uint(f);
  u += 0x7FFFu + ((u >> 16) & 1u);
  return (unsigned short)(u >> 16);
}
__device__ __forceinline__ float bf16_to_f(unsigned short h) {
  return __uint_as_float(((unsigned)h) << 16);
}

// ---------------- fast accurate double log (~1e-13 rel) ----------------
__device__ __forceinline__ double dlog(double x) {
  unsigned long long ub = (unsigned long long)__double_as_longlong(x);
  int e = (int)((ub >> 52) & 0x7FFull) - 1022;
  double m = __longlong_as_double((long long)((ub & 0x000FFFFFFFFFFFFFull) | 0x3FE0000000000000ull));
  if (m < 0.70710678118654752440) { m *= 2.0; e -= 1; }
  double r = (m - 1.0) / (m + 1.0);
  double z = r * r;
  double s = fma(z, fma(z, fma(z, fma(z, fma(z, fma(z, 1.0/15.0, 1.0/13.0),
                1.0/11.0), 1.0/9.0), 1.0/7.0), 1.0/5.0), 1.0/3.0);
  double t2 = 2.0 * r;
  return fma((double)e, 0.69314718055994530942, fma(t2 * z, s, t2));
}

__device__ __forceinline__ float gumbel_from_u(float f) {
  float uu = (f == 0.0f) ? 1.17549435e-38f : f;
  float t1 = (float)dlog((double)uu);
  return -(float)dlog((double)(-t1));
}

__device__ __forceinline__ float gumbel_of(unsigned kk0, unsigned kk1, unsigned n) {
  return gumbel_from_u(bits_to_unit(tf_xor(kk0, kk1, 0u, n)));
}

__device__ __forceinline__ double blockReduce256(double v, double* lds) {
  #pragma unroll
  for (int off = 32; off > 0; off >>= 1) v += __shfl_down(v, off);
  __syncthreads();
  if ((threadIdx.x & 63) == 0) lds[threadIdx.x >> 6] = v;
  __syncthreads();
  return lds[0] + lds[1] + lds[2] + lds[3];
}

// ---------------- K0: all small RNG draws ----------------
__global__ void k_rng(unsigned* __restrict__ keys_out, int* __restrict__ radius,
                      float* __restrict__ u_acc) {
  int t = threadIdx.x;
  unsigned krad0, krad1, ksamp0, ksamp1, kacc0, kacc1;
  tf2x32(0u, 42u, 0u, 0u, krad0, krad1);
  tf2x32(0u, 42u, 0u, 1u, ksamp0, ksamp1);
  tf2x32(0u, 42u, 0u, 2u, kacc0, kacc1);
  if (t < MAXR) {
    unsigned a, c;
    tf2x32(ksamp0, ksamp1, 0u, (unsigned)t, a, c);
    keys_out[2*t] = a; keys_out[2*t+1] = c;
  }
  unsigned k10, k11, k20, k21;
  tf2x32(krad0, krad1, 0u, 0u, k10, k11);
  tf2x32(krad0, krad1, 0u, 1u, k20, k21);
  unsigned hi = tf_xor(k10, k11, 0u, (unsigned)t);
  unsigned lo = tf_xor(k20, k21, 0u, (unsigned)t);
  unsigned off = ((hi % 31u) * 4u + (lo % 31u)) % 31u;
  radius[t] = 1 + (int)off;
  unsigned ab = tf_xor(kacc0, kacc1, 0u, (unsigned)t);
  u_acc[t] = bits_to_unit(ab);
}

// ---------------- K1a: x fp32 -> bf16 (exact: x is 0/1) ----------------
__global__ void k_xcvt(const float* __restrict__ x, unsigned short* __restrict__ xb) {
  int i = (blockIdx.x * 256 + threadIdx.x) * 8;
  float4 a = *(const float4*)&x[i];
  float4 b = *(const float4*)&x[i + 4];
  union { unsigned short u[8]; int4 v; } pk;
  pk.u[0] = rne_bf16(a.x); pk.u[1] = rne_bf16(a.y);
  pk.u[2] = rne_bf16(a.z); pk.u[3] = rne_bf16(a.w);
  pk.u[4] = rne_bf16(b.x); pk.u[5] = rne_bf16(b.y);
  pk.u[6] = rne_bf16(b.z); pk.u[7] = rne_bf16(b.w);
  *(int4*)&xb[i] = pk.v;
}

// ---------------- K1b: MFMA 3-limb bf16 GEMM, LDS-staged A via W symmetry ----------------
// grad^T = W * x^T. A-tile [k][m] staged coalesced (W row k contiguous in m, W==W^T
// bit-exactly), padded stride 65 (2-way bank conflicts only). B = xb global 16B gathers.
// grid: (DD/64 m-tiles, 2 n-halves, KC k-chunks). 4 waves/block, wave owns 16 m-rows.
__global__ __launch_bounds__(256, 3) void k_gemm_mfma(const unsigned short* __restrict__ xb,
                                                      const float* __restrict__ W,
                                                      float* __restrict__ Cpart, int klen) {
  int mt = blockIdx.x, nb = blockIdx.y, kc = blockIdx.z;
  int t = threadIdx.x;
  int wave = t >> 6, lane = t & 63;
  int quad = lane >> 4, lr = lane & 15;
  int m0 = mt * 64;
  int k0 = kc * klen;
  int nsteps = klen / 32;

  __shared__ float At[2][32 * 65 + 8];   // [k][m], stride 65 (pad)

  f32x4 acc[8];
  #pragma unroll
  for (int c = 0; c < 8; c++) acc[c] = (f32x4){0.f, 0.f, 0.f, 0.f};

  // staging: thread t -> k-row (t>>3), m-cols (t&7)*8..+8 (global contiguous 256B/row)
  int srow = t >> 3, scol = (t & 7) * 8;
  const float* gsrc = W + (size_t)(k0 + srow) * DD + m0 + scol;

  {
    float4 a = *(const float4*)gsrc;
    float4 b = *(const float4*)(gsrc + 4);
    float* dst = &At[0][srow * 65 + scol];
    dst[0]=a.x; dst[1]=a.y; dst[2]=a.z; dst[3]=a.w;
    dst[4]=b.x; dst[5]=b.y; dst[6]=b.z; dst[7]=b.w;
  }

  for (int s = 0; s < nsteps; s++) {
    __syncthreads();
    // stage next k-slab into the other buffer (overlaps with this step's MFMAs)
    if (s + 1 < nsteps) {
      const float* g = gsrc + (size_t)(s + 1) * 32 * DD;
      float4 a = *(const float4*)g;
      float4 b = *(const float4*)(g + 4);
      float* dst = &At[(s + 1) & 1][srow * 65 + scol];
      dst[0]=a.x; dst[1]=a.y; dst[2]=a.z; dst[3]=a.w;
      dst[4]=b.x; dst[5]=b.y; dst[6]=b.z; dst[7]=b.w;
    }
    // A-frag: A[m = wave*16+lr][k = quad*8+j] from LDS [k][m] (stride-65 b32, 2-way)
    float af[8];
    const float* src = &At[s & 1][(quad * 8) * 65 + wave * 16 + lr];
    #pragma unroll
    for (int j = 0; j < 8; j++) af[j] = src[j * 65];
    // 3-limb Dekker split (exact residuals)
    bf16x8 hi, mi, lo;
    #pragma unroll
    for (int j = 0; j < 8; j++) {
      unsigned short h = rne_bf16(af[j]);
      float r1 = af[j] - bf16_to_f(h);
      unsigned short m = rne_bf16(r1);
      float r2 = r1 - bf16_to_f(m);
      unsigned short l = rne_bf16(r2);
      hi[j] = (short)h; mi[j] = (short)m; lo[j] = (short)l;
    }
    // B-frags: 8 n-tiles of this n-half, per-lane 16B contiguous (L2-resident)
    int kb = k0 + s * 32 + quad * 8;
    bf16x8 bfr[8];
    #pragma unroll
    for (int c = 0; c < 8; c++) {
      const unsigned short* bp = xb + (size_t)(nb * 128 + c * 16 + lr) * DD + kb;
      bfr[c] = *(const bf16x8*)bp;
    }
    #pragma unroll
    for (int c = 0; c < 8; c++) {
      acc[c] = __builtin_amdgcn_mfma_f32_16x16x32_bf16(lo, bfr[c], acc[c], 0, 0, 0);
      acc[c] = __builtin_amdgcn_mfma_f32_16x16x32_bf16(mi, bfr[c], acc[c], 0, 0, 0);
      acc[c] = __builtin_amdgcn_mfma_f32_16x16x32_bf16(hi, bfr[c], acc[c], 0, 0, 0);
    }
  }
  // store: D row=(quad*4+r) -> m, col=lr -> batch  (C/D: col=lane&15, row=quad*4+reg)
  float* Cp = Cpart + (size_t)kc * DD * BB;
  #pragma unroll
  for (int c = 0; c < 8; c++) {
    #pragma unroll
    for (int r = 0; r < 4; r++) {
      int m = m0 + wave * 16 + quad * 4 + r;
      int b = nb * 128 + c * 16 + lr;
      Cp[(size_t)m * BB + b] = acc[c][r];
    }
  }
}

// ---------------- K1c: transposing split-K reduce + bias -> grad[b][d], sc_x ----------------
__global__ __launch_bounds__(256) void k_reduce(const float* __restrict__ Cpart,
                                                const float* __restrict__ bias,
                                                const float* __restrict__ x,
                                                float* __restrict__ grad,
                                                float* __restrict__ sc, int KC) {
  __shared__ float tile[64][65];
  int d0 = blockIdx.x * 64, b0 = blockIdx.y * 64;
  int t = threadIdx.x;
  int j = t & 63, i0 = t >> 6;
  #pragma unroll
  for (int ii = 0; ii < 16; ii++) {
    int i = i0 + 4 * ii;
    float s = 0.f;
    for (int kc = 0; kc < KC; kc++)
      s += Cpart[(size_t)kc * DD * BB + (size_t)(d0 + i) * BB + (b0 + j)];
    tile[i][j] = s + bias[d0 + i];
  }
  __syncthreads();
  #pragma unroll
  for (int ii = 0; ii < 16; ii++) {
    int bloc = i0 + 4 * ii;
    int dloc = j;
    float g = tile[dloc][bloc];
    size_t o = (size_t)(b0 + bloc) * DD + d0 + dloc;
    grad[o] = g;
    float xv = x[o];
    sc[o] = (1.0f - 2.0f * xv) * g * 0.5f;
  }
}

// ---------------- K2: score_x + per-row max of sc_x ----------------
__global__ __launch_bounds__(256) void k_score(const float* __restrict__ x, const float* __restrict__ grad,
                                               const float* __restrict__ bias, double* __restrict__ score,
                                               float* __restrict__ scmax) {
  int b = blockIdx.x, t = threadIdx.x;
  double s1 = 0.0, s2 = 0.0;
  float mx = -INFINITY;
  for (int k = 0; k < 16; k++) {
    int d = t + 256*k; size_t o = (size_t)b*DD + d;
    float xvf = x[o];
    float gv = grad[o];
    float scv = (1.0f - 2.0f*xvf) * gv * 0.5f;  // identical rounding to k_reduce
    mx = fmaxf(mx, scv);
    double xv = xvf;
    s1 += xv * (double)gv;
    s2 += xv * (double)bias[d];
  }
  __shared__ double lds[4];
  double S1 = blockReduce256(s1, lds);
  double S2 = blockReduce256(s2, lds);
  #pragma unroll
  for (int off = 32; off > 0; off >>= 1) mx = fmaxf(mx, __shfl_down(mx, off));
  __shared__ float lmx[4];
  __syncthreads();
  if ((t & 63) == 0) lmx[t >> 6] = mx;
  __syncthreads();
  if (t == 0) {
    score[b] = 0.5 * (S1 + S2);
    scmax[b] = fmaxf(fmaxf(lmx[0], lmx[1]), fmaxf(lmx[2], lmx[3]));
  }
}

// ---------------- K4: per (row,step) top-4 via u-filter + exact fallback ----------------
__global__ __launch_bounds__(256) void k_cand(const float* __restrict__ sc_x,
                                              const unsigned* __restrict__ keys,
                                              const float* __restrict__ scmax,
                                              int* __restrict__ cand_i) {
  int blk = blockIdx.x;
  int b = blk / MAXR, j = blk % MAXR;
  unsigned kk0 = keys[2*j], kk1 = keys[2*j+1];
  int t = threadIdx.x;
  unsigned base = (unsigned)(b * DD);

  __shared__ int cnt;
  __shared__ int   lidx[CAP];
  __shared__ float lu[CAP];
  __shared__ float win_v_s;
  __shared__ int   win_i_s;
  __shared__ float ls_v[4];
  __shared__ int   ls_i[4];
  if (t == 0) cnt = 0;
  __syncthreads();

  // phase 1: threefry + uniform + cheap filter (the 97.8% fast path)
  #pragma unroll
  for (int p = 0; p < 16; p++) {
    int d = t + 256*p;
    unsigned bits = tf_xor(kk0, kk1, 0u, base + (unsigned)d);
    float f = bits_to_unit(bits);
    if (f >= U_THRESH) {
      int pos = atomicAdd(&cnt, 1);
      if (pos < CAP) { lidx[pos] = d; lu[pos] = f; }
    }
  }
  __syncthreads();
  int n = cnt;
  bool need_fallback = (n > CAP) || (n < NCAND);

  if (!need_fallback) {
    // phase 2: exact gumbel + top-4 over <=512 candidates (2 per thread)
    float v[2]; int di[2]; unsigned alive = 0u;
    #pragma unroll
    for (int q = 0; q < 2; q++) {
      int idx = t + 256*q;
      if (idx < n) {
        int d = lidx[idx];
        v[q] = sc_x[(size_t)b*DD + d] + gumbel_from_u(lu[idx]);
        di[q] = d;
        alive |= (1u << q);
      } else { v[q] = -INFINITY; di[q] = 0x7FFFFFFF; }
    }
    float v4 = -INFINITY;
    for (int r = 0; r < NCAND; r++) {
      float bv = -INFINITY; int bi = 0x7FFFFFFF;
      #pragma unroll
      for (int q = 0; q < 2; q++)
        if (((alive >> q) & 1u) && (v[q] > bv || (v[q] == bv && di[q] < bi))) { bv = v[q]; bi = di[q]; }
      #pragma unroll
      for (int off = 32; off > 0; off >>= 1) {
        float ov = __shfl_down(bv, off);
        int   oi = __shfl_down(bi, off);
        if (ov > bv || (ov == bv && oi < bi)) { bv = ov; bi = oi; }
      }
      if ((t & 63) == 0) { ls_v[t >> 6] = bv; ls_i[t >> 6] = bi; }
      __syncthreads();
      if (t == 0) {
        float fv = ls_v[0]; int fi = ls_i[0];
        #pragma unroll
        for (int w = 1; w < 4; w++)
          if (ls_v[w] > fv || (ls_v[w] == fv && ls_i[w] < fi)) { fv = ls_v[w]; fi = ls_i[w]; }
        win_v_s = fv; win_i_s = fi;
        cand_i[(size_t)blk * NCAND + r] = fi;
      }
      __syncthreads();
      int wd = win_i_s;
      v4 = win_v_s;
      #pragma unroll
      for (int q = 0; q < 2; q++) if (di[q] == wd) alive &= ~(1u << q);
    }
    // guarantee: every skipped element has v < scmax + 3.8 < scmax + GUARD
    if (v4 >= scmax[b] + GUARD) return;
    need_fallback = true;
    __syncthreads();
  }

  // fallback: full exact computation (statistically ~never; preserves exactness)
  {
    float v[16];
    #pragma unroll
    for (int p = 0; p < 16; p++) {
      int d = t + 256*p;
      v[p] = sc_x[(size_t)b*DD + d] + gumbel_of(kk0, kk1, base + (unsigned)d);
    }
    unsigned alive = 0xFFFFu;
    float lv = -INFINITY; int li = 0x7FFFFFFF;
    #pragma unroll
    for (int p = 0; p < 16; p++)
      if (v[p] > lv) { lv = v[p]; li = t + 256*p; }
    for (int r = 0; r < NCAND; r++) {
      float bv = lv; int bi = li;
      #pragma unroll
      for (int off = 32; off > 0; off >>= 1) {
        float ov = __shfl_down(bv, off);
        int   oi = __shfl_down(bi, off);
        if (ov > bv || (ov == bv && oi < bi)) { bv = ov; bi = oi; }
      }
      if ((t & 63) == 0) { ls_v[t >> 6] = bv; ls_i[t >> 6] = bi; }
      __syncthreads();
      if (t == 0) {
        float fv = ls_v[0]; int fi = ls_i[0];
        #pragma unroll
        for (int w = 1; w < 4; w++)
          if (ls_v[w] > fv || (ls_v[w] == fv && ls_i[w] < fi)) { fv = ls_v[w]; fi = ls_i[w]; }
        win_i_s = fi;
        cand_i[(size_t)blk * NCAND + r] = fi;
      }
      __syncthreads();
      if (r < NCAND - 1) {
        int wi = win_i_s;
        if (t == (wi & 255)) {
          alive &= ~(1u << (wi >> 8));
          lv = -INFINITY; li = 0x7FFFFFFF;
          #pragma unroll
          for (int p = 0; p < 16; p++)
            if (((alive >> p) & 1u) && v[p] > lv) { lv = v[p]; li = t + 256*p; }
        }
      }
    }
  }
}

// ---------------- K5: per-row blocked-chain resolution w/ exact fallback ----------------
__global__ __launch_bounds__(256) void k_select(const int* __restrict__ cand_i,
                                                const float* __restrict__ sc_x,
                                                const unsigned* __restrict__ keys,
                                                int* __restrict__ idx_all) {
  int b = blockIdx.x, t = threadIdx.x;
  __shared__ unsigned mask[128];
  __shared__ int pick_s;
  __shared__ float ls_v[4];
  __shared__ int   ls_i[4];
  if (t < 128) mask[t] = 0u;
  __syncthreads();
  for (int j = 0; j < MAXR; j++) {
    if (t == 0) {
      const int* ci = &cand_i[(size_t)(b*MAXR + j) * NCAND];
      int pick = -1;
      #pragma unroll
      for (int r = 0; r < NCAND; r++) {
        int idx = ci[r];
        if (pick < 0 && !((mask[idx >> 5] >> (idx & 31)) & 1u)) pick = idx;
      }
      pick_s = pick;
    }
    __syncthreads();
    if (pick_s < 0) {
      unsigned kk0 = keys[2*j], kk1 = keys[2*j+1];
      float lv = -INFINITY; int li = 0x7FFFFFFF;
      for (int p = 0; p < 16; p++) {
        int d = t + 256*p;
        if ((mask[d >> 5] >> (d & 31)) & 1u) continue;
        float vv = sc_x[(size_t)b*DD + d] + gumbel_of(kk0, kk1, (unsigned)(b*DD + d));
        if (vv > lv || (vv == lv && d < li)) { lv = vv; li = d; }
      }
      float bv = lv; int bi = li;
      #pragma unroll
      for (int off = 32; off > 0; off >>= 1) {
        float ov = __shfl_down(bv, off);
        int   oi = __shfl_down(bi, off);
        if (ov > bv || (ov == bv && oi < bi)) { bv = ov; bi = oi; }
      }
      if ((t & 63) == 0) { ls_v[t >> 6] = bv; ls_i[t >> 6] = bi; }
      __syncthreads();
      if (t == 0) {
        float fv = ls_v[0]; int fi = ls_i[0];
        #pragma unroll
        for (int w = 1; w < 4; w++)
          if (ls_v[w] > fv || (ls_v[w] == fv && ls_i[w] < fi)) { fv = ls_v[w]; fi = ls_i[w]; }
        pick_s = fi;
      }
      __syncthreads();
    }
    if (t == 0) {
      int pk = pick_s;
      idx_all[b*MAXR + j] = pk;
      mask[pk >> 5] |= (1u << (pk & 31));
    }
    __syncthreads();
  }
}

// ---------------- K6: y, grad_y (incremental), sc_y, score_y ----------------
__global__ __launch_bounds__(256) void k_y(const float* __restrict__ x, const float* __restrict__ W,
    const float* __restrict__ bias, const float* __restrict__ grad_x,
    const int* __restrict__ idx_all, const int* __restrict__ radius,
    float* __restrict__ yv, float* __restrict__ sc_y, double* __restrict__ score_y) {
  int b = blockIdx.x, t = threadIdx.x;
  __shared__ int   fidx[MAXR];
  __shared__ float fsgn[MAXR];
  int nf = radius[b];
  if (t < nf) {
    int id = idx_all[b*MAXR + t];
    fidx[t] = id;
    fsgn[t] = 1.0f - 2.0f * x[(size_t)b*DD + id];
  }
  __syncthreads();
  double s1 = 0.0, s2 = 0.0;
  for (int k = 0; k < 16; k++) {
    int d = t + 256*k;
    size_t o = (size_t)b*DD + d;
    float g = grad_x[o];
    float xval = x[o];
    float yval = xval;
    for (int jj = 0; jj < nf; jj++) {
      g = fmaf(fsgn[jj], W[(size_t)fidx[jj]*DD + d], g);
      if (fidx[jj] == d) yval = 1.0f - xval;
    }
    yv[o] = yval;
    sc_y[o] = (1.0f - 2.0f*yval) * g * 0.5f;
    s1 += (double)yval * (double)g;
    s2 += (double)yval * (double)bias[d];
  }
  __shared__ double lds[4];
  double S1 = blockReduce256(s1, lds);
  double S2 = blockReduce256(s2, lds);
  if (t == 0) score_y[b] = 0.5 * (S1 + S2);
}

// ---------------- K7: masked log-softmax sums, accept, output ----------------
__global__ __launch_bounds__(256) void k_accept(const float* __restrict__ x, const float* __restrict__ yv,
    const float* __restrict__ sc_x, const float* __restrict__ sc_y,
    const int* __restrict__ idx_all, const int* __restrict__ radius,
    const double* __restrict__ score_x, const double* __restrict__ score_y,
    const float* __restrict__ u_acc, float* __restrict__ out) {
  int b = blockIdx.x, t = threadIdx.x;
  double sx = 0.0, sy = 0.0;
  for (int k = 0; k < 16; k++) {
    int d = t + 256*k; size_t o = (size_t)b*DD + d;
    sx += exp((double)sc_x[o]);
    sy += exp((double)sc_y[o]);
  }
  __shared__ double lds[4];
  double S = blockReduce256(sx, lds);
  double T = blockReduce256(sy, lds);
  __shared__ float accf;
  if (t == 0) {
    int nf = radius[b];
    const int* ia = &idx_all[b*MAXR];
    double lf = 0.0, pre = 0.0;
    for (int jj = 0; jj < MAXR; jj++) {
      int id = ia[jj];
      double scv = (double)sc_x[(size_t)b*DD + id];
      if (jj < nf) lf += scv - dlog(S - pre);
      pre += exp(scv);
    }
    double lb = 0.0, suf = 0.0;
    for (int jj = MAXR-1; jj >= 0; jj--) {
      int id = ia[jj];
      double scv = (double)sc_y[(size_t)b*DD + id];
      if (jj < nf) lb += scv - dlog(T - suf);
      suf += exp(scv);
    }
    double log_acc = (lb + score_y[b]) - (lf + score_x[b]);
    accf = (exp(log_acc) >= (double)u_acc[b]) ? 1.0f : 0.0f;
  }
  __syncthreads();
  float a = accf;
  for (int k = 0; k < 16; k++) {
    int d = t + 256*k; size_t o = (size_t)b*DD + d;
    out[o] = a * yv[o] + (1.0f - a) * x[o];
  }
}

extern "C" void kernel_launch(void* const* d_in, const int* in_sizes, int n_in,
                              void* d_out, int out_size, void* d_ws, size_t ws_size,
                              hipStream_t stream) {
  const float* x    = (const float*)d_in[0];
  const float* W    = (const float*)d_in[1];
  const float* bias = (const float*)d_in[2];
  float* out = (float*)d_out;
  char* ws = (char*)d_ws;
  const size_t MB = 1ull << 20;

  float*          grad_x  = (float*)         (ws + 0*MB);
  float*          sc_x    = (float*)         (ws + 4*MB);
  float*          sc_y    = (float*)         (ws + 8*MB);
  float*          yv      = (float*)         (ws + 12*MB);
  unsigned short* xb      = (unsigned short*)(ws + 16*MB);
  int*            cand_i  = (int*)           (ws + 20*MB);
  int*            idx_all = (int*)           (ws + 21*MB);
  int*            radius  = (int*)           (ws + 21*MB + 64*1024);
  float*          u_acc   = (float*)         (ws + 21*MB + 68*1024);
  unsigned*       keys    = (unsigned*)      (ws + 21*MB + 72*1024);
  double*         score_x = (double*)        (ws + 21*MB + 80*1024);
  double*         score_y = (double*)        (ws + 21*MB + 96*1024);
  float*          scmax   = (float*)         (ws + 21*MB + 112*1024);
  float*          Cpart   = (float*)         (ws + 22*MB);

  size_t base = 22*MB;
  int KC = 1;
  if      (ws_size >= base + 32*MB) KC = 8;
  else if (ws_size >= base + 16*MB) KC = 4;
  else if (ws_size >= base +  8*MB) KC = 2;

  k_rng      <<<1, 256, 0, stream>>>(keys, radius, u_acc);
  k_xcvt     <<<512, 256, 0, stream>>>(x, xb);
  k_gemm_mfma<<<dim3(DD/64, 2, KC), 256, 0, stream>>>(xb, W, Cpart, DD/KC);
  k_reduce   <<<dim3(DD/64, BB/64), 256, 0, stream>>>(Cpart, bias, x, grad_x, sc_x, KC);
  k_score    <<<BB, 256, 0, stream>>>(x, grad_x, bias, score_x, scmax);
  k_cand     <<<BB*MAXR, 256, 0, stream>>>(sc_x, keys, scmax, cand_i);
  k_select   <<<BB, 256, 0, stream>>>(cand_i, sc_x, keys, idx_all);
  k_y        <<<BB, 256, 0, stream>>>(x, W, bias, grad_x, idx_all, radius, yv, sc_y, score_y);
  k_accept   <<<BB, 256, 0, stream>>>(x, yv, sc_x, sc_y, idx_all, radius, score_x, score_y, u_acc, out);
}

// Round 6
// 375.072 us; speedup vs baseline: 1.0335x; 1.0040x over previous
//
#include <hip/hip_runtime.h>
#include <math.h>

#define BB 256
#define DD 4096
#define MAXR 31
#define NCAND 4
#define CAP 512
// filter: u < U_THRESH  =>  g(u) < 3.8 (incl. fp32 rounding slop). GUARD=4.0 check.
// integer-domain equivalent of (bits_to_unit(bits) >= 0.9778f):
//   f = (bits>>9)*2^-23 exactly; 0.9778f = 16404971*2^-24  =>  bits >= 8202486<<9
#define IBITS_THRESH 4199672832u
#define GUARD 4.0f

typedef float f32x4 __attribute__((ext_vector_type(4)));
typedef short bf16x8 __attribute__((ext_vector_type(8)));

// rotate-left as single v_alignbit_b32 (alignbit(a,b,s) = ((a:b)>>s); a==b => rotr(v,s))
__device__ __forceinline__ unsigned rotl32(unsigned v, unsigned r) {
  return __builtin_amdgcn_alignbit(v, v, 32u - r);
}

// ---------------- threefry2x32 (JAX schedule) ----------------
__device__ __forceinline__ void tf2x32(unsigned k0, unsigned k1, unsigned c0, unsigned c1,
                                       unsigned &o0, unsigned &o1) {
  unsigned ks2 = k0 ^ k1 ^ 0x1BD11BDAu;
  unsigned x0 = c0 + k0;
  unsigned x1 = c1 + k1;
#define TF_R(r) { x0 += x1; x1 = rotl32(x1, r); x1 ^= x0; }
  TF_R(13) TF_R(15) TF_R(26) TF_R(6)   x0 += k1;  x1 += ks2 + 1u;
  TF_R(17) TF_R(29) TF_R(16) TF_R(24)  x0 += ks2; x1 += k0 + 2u;
  TF_R(13) TF_R(15) TF_R(26) TF_R(6)   x0 += k0;  x1 += k1 + 3u;
  TF_R(17) TF_R(29) TF_R(16) TF_R(24)  x0 += k1;  x1 += ks2 + 4u;
  TF_R(13) TF_R(15) TF_R(26) TF_R(6)   x0 += ks2; x1 += k0 + 5u;
#undef TF_R
  o0 = x0; o1 = x1;
}

__device__ __forceinline__ unsigned tf_xor(unsigned k0, unsigned k1, unsigned c0, unsigned c1) {
  unsigned a, b; tf2x32(k0, k1, c0, c1, a, b); return a ^ b;
}

__device__ __forceinline__ float bits_to_unit(unsigned bits) {
  return __uint_as_float(0x3f800000u | (bits >> 9)) - 1.0f;
}

// ---------------- bf16 helpers (RNE) ----------------
__device__ __forceinline__ unsigned short rne_bf16(float f) {
  unsigned u = __float_as_uint(f);
  u += 0x7FFFu + ((u >> 16) & 1u);
  return (unsigned short)(u >> 16);
}
__device__ __forceinline__ float bf16_to_f(unsigned short h) {
  return __uint_as_float(((unsigned)h) << 16);
}

// ---------------- fast accurate double log (~1e-13 rel) ----------------
__device__ __forceinline__ double dlog(double x) {
  unsigned long long ub = (unsigned long long)__double_as_longlong(x);
  int e = (int)((ub >> 52) & 0x7FFull) - 1022;
  double m = __longlong_as_double((long long)((ub & 0x000FFFFFFFFFFFFFull) | 0x3FE0000000000000ull));
  if (m < 0.70710678118654752440) { m *= 2.0; e -= 1; }
  double r = (m - 1.0) / (m + 1.0);
  double z = r * r;
  double s = fma(z, fma(z, fma(z, fma(z, fma(z, fma(z, 1.0/15.0, 1.0/13.0),
                1.0/11.0), 1.0/9.0), 1.0/7.0), 1.0/5.0), 1.0/3.0);
  double t2 = 2.0 * r;
  return fma((double)e, 0.69314718055994530942, fma(t2 * z, s, t2));
}

__device__ __forceinline__ float gumbel_from_u(float f) {
  float uu = (f == 0.0f) ? 1.17549435e-38f : f;
  float t1 = (float)dlog((double)uu);
  return -(float)dlog((double)(-t1));
}

__device__ __forceinline__ float gumbel_of(unsigned kk0, unsigned kk1, unsigned n) {
  return gumbel_from_u(bits_to_unit(tf_xor(kk0, kk1, 0u, n)));
}

__device__ __forceinline__ double blockReduce256(double v, double* lds) {
  #pragma unroll
  for (int off = 32; off > 0; off >>= 1) v += __shfl_down(v, off);
  __syncthreads();
  if ((threadIdx.x & 63) == 0) lds[threadIdx.x >> 6] = v;
  __syncthreads();
  return lds[0] + lds[1] + lds[2] + lds[3];
}

// ---------------- K0: all small RNG draws ----------------
__global__ void k_rng(unsigned* __restrict__ keys_out, int* __restrict__ radius,
                      float* __restrict__ u_acc) {
  int t = threadIdx.x;
  unsigned krad0, krad1, ksamp0, ksamp1, kacc0, kacc1;
  tf2x32(0u, 42u, 0u, 0u, krad0, krad1);
  tf2x32(0u, 42u, 0u, 1u, ksamp0, ksamp1);
  tf2x32(0u, 42u, 0u, 2u, kacc0, kacc1);
  if (t < MAXR) {
    unsigned a, c;
    tf2x32(ksamp0, ksamp1, 0u, (unsigned)t, a, c);
    keys_out[2*t] = a; keys_out[2*t+1] = c;
  }
  unsigned k10, k11, k20, k21;
  tf2x32(krad0, krad1, 0u, 0u, k10, k11);
  tf2x32(krad0, krad1, 0u, 1u, k20, k21);
  unsigned hi = tf_xor(k10, k11, 0u, (unsigned)t);
  unsigned lo = tf_xor(k20, k21, 0u, (unsigned)t);
  unsigned off = ((hi % 31u) * 4u + (lo % 31u)) % 31u;
  radius[t] = 1 + (int)off;
  unsigned ab = tf_xor(kacc0, kacc1, 0u, (unsigned)t);
  u_acc[t] = bits_to_unit(ab);
}

// ---------------- K1a: x fp32 -> bf16 (exact: x is 0/1) ----------------
__global__ void k_xcvt(const float* __restrict__ x, unsigned short* __restrict__ xb) {
  int i = (blockIdx.x * 256 + threadIdx.x) * 8;
  float4 a = *(const float4*)&x[i];
  float4 b = *(const float4*)&x[i + 4];
  union { unsigned short u[8]; int4 v; } pk;
  pk.u[0] = rne_bf16(a.x); pk.u[1] = rne_bf16(a.y);
  pk.u[2] = rne_bf16(a.z); pk.u[3] = rne_bf16(a.w);
  pk.u[4] = rne_bf16(b.x); pk.u[5] = rne_bf16(b.y);
  pk.u[6] = rne_bf16(b.z); pk.u[7] = rne_bf16(b.w);
  *(int4*)&xb[i] = pk.v;
}

// ---------------- K1b: MFMA 3-limb bf16 GEMM, LDS-staged A via W symmetry ----------------
__global__ __launch_bounds__(256, 3) void k_gemm_mfma(const unsigned short* __restrict__ xb,
                                                      const float* __restrict__ W,
                                                      float* __restrict__ Cpart, int klen) {
  int mt = blockIdx.x, nb = blockIdx.y, kc = blockIdx.z;
  int t = threadIdx.x;
  int wave = t >> 6, lane = t & 63;
  int quad = lane >> 4, lr = lane & 15;
  int m0 = mt * 64;
  int k0 = kc * klen;
  int nsteps = klen / 32;

  __shared__ float At[2][32 * 65 + 8];   // [k][m], stride 65 (pad)

  f32x4 acc[8];
  #pragma unroll
  for (int c = 0; c < 8; c++) acc[c] = (f32x4){0.f, 0.f, 0.f, 0.f};

  int srow = t >> 3, scol = (t & 7) * 8;
  const float* gsrc = W + (size_t)(k0 + srow) * DD + m0 + scol;

  {
    float4 a = *(const float4*)gsrc;
    float4 b = *(const float4*)(gsrc + 4);
    float* dst = &At[0][srow * 65 + scol];
    dst[0]=a.x; dst[1]=a.y; dst[2]=a.z; dst[3]=a.w;
    dst[4]=b.x; dst[5]=b.y; dst[6]=b.z; dst[7]=b.w;
  }

  for (int s = 0; s < nsteps; s++) {
    __syncthreads();
    if (s + 1 < nsteps) {
      const float* g = gsrc + (size_t)(s + 1) * 32 * DD;
      float4 a = *(const float4*)g;
      float4 b = *(const float4*)(g + 4);
      float* dst = &At[(s + 1) & 1][srow * 65 + scol];
      dst[0]=a.x; dst[1]=a.y; dst[2]=a.z; dst[3]=a.w;
      dst[4]=b.x; dst[5]=b.y; dst[6]=b.z; dst[7]=b.w;
    }
    float af[8];
    const float* src = &At[s & 1][(quad * 8) * 65 + wave * 16 + lr];
    #pragma unroll
    for (int j = 0; j < 8; j++) af[j] = src[j * 65];
    bf16x8 hi, mi, lo;
    #pragma unroll
    for (int j = 0; j < 8; j++) {
      unsigned short h = rne_bf16(af[j]);
      float r1 = af[j] - bf16_to_f(h);
      unsigned short m = rne_bf16(r1);
      float r2 = r1 - bf16_to_f(m);
      unsigned short l = rne_bf16(r2);
      hi[j] = (short)h; mi[j] = (short)m; lo[j] = (short)l;
    }
    int kb = k0 + s * 32 + quad * 8;
    bf16x8 bfr[8];
    #pragma unroll
    for (int c = 0; c < 8; c++) {
      const unsigned short* bp = xb + (size_t)(nb * 128 + c * 16 + lr) * DD + kb;
      bfr[c] = *(const bf16x8*)bp;
    }
    #pragma unroll
    for (int c = 0; c < 8; c++) {
      acc[c] = __builtin_amdgcn_mfma_f32_16x16x32_bf16(lo, bfr[c], acc[c], 0, 0, 0);
      acc[c] = __builtin_amdgcn_mfma_f32_16x16x32_bf16(mi, bfr[c], acc[c], 0, 0, 0);
      acc[c] = __builtin_amdgcn_mfma_f32_16x16x32_bf16(hi, bfr[c], acc[c], 0, 0, 0);
    }
  }
  float* Cp = Cpart + (size_t)kc * DD * BB;
  #pragma unroll
  for (int c = 0; c < 8; c++) {
    #pragma unroll
    for (int r = 0; r < 4; r++) {
      int m = m0 + wave * 16 + quad * 4 + r;
      int b = nb * 128 + c * 16 + lr;
      Cp[(size_t)m * BB + b] = acc[c][r];
    }
  }
}

// ---------------- K1c: transposing split-K reduce + bias -> grad[b][d], sc_x ----------------
__global__ __launch_bounds__(256) void k_reduce(const float* __restrict__ Cpart,
                                                const float* __restrict__ bias,
                                                const float* __restrict__ x,
                                                float* __restrict__ grad,
                                                float* __restrict__ sc, int KC) {
  __shared__ float tile[64][65];
  int d0 = blockIdx.x * 64, b0 = blockIdx.y * 64;
  int t = threadIdx.x;
  int j = t & 63, i0 = t >> 6;
  #pragma unroll
  for (int ii = 0; ii < 16; ii++) {
    int i = i0 + 4 * ii;
    float s = 0.f;
    for (int kc = 0; kc < KC; kc++)
      s += Cpart[(size_t)kc * DD * BB + (size_t)(d0 + i) * BB + (b0 + j)];
    tile[i][j] = s + bias[d0 + i];
  }
  __syncthreads();
  #pragma unroll
  for (int ii = 0; ii < 16; ii++) {
    int bloc = i0 + 4 * ii;
    int dloc = j;
    float g = tile[dloc][bloc];
    size_t o = (size_t)(b0 + bloc) * DD + d0 + dloc;
    grad[o] = g;
    float xv = x[o];
    sc[o] = (1.0f - 2.0f * xv) * g * 0.5f;
  }
}

// ---------------- K2: score_x + per-row max of sc_x ----------------
__global__ __launch_bounds__(256) void k_score(const float* __restrict__ x, const float* __restrict__ grad,
                                               const float* __restrict__ bias, double* __restrict__ score,
                                               float* __restrict__ scmax) {
  int b = blockIdx.x, t = threadIdx.x;
  double s1 = 0.0, s2 = 0.0;
  float mx = -INFINITY;
  for (int k = 0; k < 16; k++) {
    int d = t + 256*k; size_t o = (size_t)b*DD + d;
    float xvf = x[o];
    float gv = grad[o];
    float scv = (1.0f - 2.0f*xvf) * gv * 0.5f;  // identical rounding to k_reduce
    mx = fmaxf(mx, scv);
    double xv = xvf;
    s1 += xv * (double)gv;
    s2 += xv * (double)bias[d];
  }
  __shared__ double lds[4];
  double S1 = blockReduce256(s1, lds);
  double S2 = blockReduce256(s2, lds);
  #pragma unroll
  for (int off = 32; off > 0; off >>= 1) mx = fmaxf(mx, __shfl_down(mx, off));
  __shared__ float lmx[4];
  __syncthreads();
  if ((t & 63) == 0) lmx[t >> 6] = mx;
  __syncthreads();
  if (t == 0) {
    score[b] = 0.5 * (S1 + S2);
    scmax[b] = fmaxf(fmaxf(lmx[0], lmx[1]), fmaxf(lmx[2], lmx[3]));
  }
}

// ---------------- K4: per (row,step) top-4 via integer u-filter + exact fallback ----------------
__global__ __launch_bounds__(256) void k_cand(const float* __restrict__ sc_x,
                                              const unsigned* __restrict__ keys,
                                              const float* __restrict__ scmax,
                                              int* __restrict__ cand_i) {
  int blk = blockIdx.x;
  int b = blk / MAXR, j = blk % MAXR;
  unsigned kk0 = keys[2*j], kk1 = keys[2*j+1];
  int t = threadIdx.x;
  unsigned base = (unsigned)(b * DD);

  __shared__ int cnt;
  __shared__ int      lidx[CAP];
  __shared__ unsigned lbits[CAP];
  __shared__ float win_v_s;
  __shared__ int   win_i_s;
  __shared__ float ls_v[4];
  __shared__ int   ls_i[4];
  if (t == 0) cnt = 0;
  __syncthreads();

  // phase 1: threefry + single integer compare (the ~97.8% fast path)
  #pragma unroll
  for (int p = 0; p < 16; p++) {
    int d = t + 256*p;
    unsigned bits = tf_xor(kk0, kk1, 0u, base + (unsigned)d);
    if (bits >= IBITS_THRESH) {
      int pos = atomicAdd(&cnt, 1);
      if (pos < CAP) { lidx[pos] = d; lbits[pos] = bits; }
    }
  }
  __syncthreads();
  int n = cnt;
  bool need_fallback = (n > CAP) || (n < NCAND);

  if (!need_fallback) {
    // phase 2: exact gumbel + top-4 over <=512 candidates (2 per thread)
    float v[2]; int di[2]; unsigned alive = 0u;
    #pragma unroll
    for (int q = 0; q < 2; q++) {
      int idx = t + 256*q;
      if (idx < n) {
        int d = lidx[idx];
        v[q] = sc_x[(size_t)b*DD + d] + gumbel_from_u(bits_to_unit(lbits[idx]));
        di[q] = d;
        alive |= (1u << q);
      } else { v[q] = -INFINITY; di[q] = 0x7FFFFFFF; }
    }
    float v4 = -INFINITY;
    for (int r = 0; r < NCAND; r++) {
      float bv = -INFINITY; int bi = 0x7FFFFFFF;
      #pragma unroll
      for (int q = 0; q < 2; q++)
        if (((alive >> q) & 1u) && (v[q] > bv || (v[q] == bv && di[q] < bi))) { bv = v[q]; bi = di[q]; }
      #pragma unroll
      for (int off = 32; off > 0; off >>= 1) {
        float ov = __shfl_down(bv, off);
        int   oi = __shfl_down(bi, off);
        if (ov > bv || (ov == bv && oi < bi)) { bv = ov; bi = oi; }
      }
      if ((t & 63) == 0) { ls_v[t >> 6] = bv; ls_i[t >> 6] = bi; }
      __syncthreads();
      if (t == 0) {
        float fv = ls_v[0]; int fi = ls_i[0];
        #pragma unroll
        for (int w = 1; w < 4; w++)
          if (ls_v[w] > fv || (ls_v[w] == fv && ls_i[w] < fi)) { fv = ls_v[w]; fi = ls_i[w]; }
        win_v_s = fv; win_i_s = fi;
        cand_i[(size_t)blk * NCAND + r] = fi;
      }
      __syncthreads();
      int wd = win_i_s;
      v4 = win_v_s;
      #pragma unroll
      for (int q = 0; q < 2; q++) if (di[q] == wd) alive &= ~(1u << q);
    }
    // guarantee: every skipped element has v < scmax + 3.8 < scmax + GUARD
    if (v4 >= scmax[b] + GUARD) return;
    need_fallback = true;
    __syncthreads();
  }

  // fallback: full exact computation (statistically ~never; preserves exactness)
  {
    float v[16];
    #pragma unroll
    for (int p = 0; p < 16; p++) {
      int d = t + 256*p;
      v[p] = sc_x[(size_t)b*DD + d] + gumbel_of(kk0, kk1, base + (unsigned)d);
    }
    unsigned alive = 0xFFFFu;
    float lv = -INFINITY; int li = 0x7FFFFFFF;
    #pragma unroll
    for (int p = 0; p < 16; p++)
      if (v[p] > lv) { lv = v[p]; li = t + 256*p; }
    for (int r = 0; r < NCAND; r++) {
      float bv = lv; int bi = li;
      #pragma unroll
      for (int off = 32; off > 0; off >>= 1) {
        float ov = __shfl_down(bv, off);
        int   oi = __shfl_down(bi, off);
        if (ov > bv || (ov == bv && oi < bi)) { bv = ov; bi = oi; }
      }
      if ((t & 63) == 0) { ls_v[t >> 6] = bv; ls_i[t >> 6] = bi; }
      __syncthreads();
      if (t == 0) {
        float fv = ls_v[0]; int fi = ls_i[0];
        #pragma unroll
        for (int w = 1; w < 4; w++)
          if (ls_v[w] > fv || (ls_v[w] == fv && ls_i[w] < fi)) { fv = ls_v[w]; fi = ls_i[w]; }
        win_i_s = fi;
        cand_i[(size_t)blk * NCAND + r] = fi;
      }
      __syncthreads();
      if (r < NCAND - 1) {
        int wi = win_i_s;
        if (t == (wi & 255)) {
          alive &= ~(1u << (wi >> 8));
          lv = -INFINITY; li = 0x7FFFFFFF;
          #pragma unroll
          for (int p = 0; p < 16; p++)
            if (((alive >> p) & 1u) && v[p] > lv) { lv = v[p]; li = t + 256*p; }
        }
      }
    }
  }
}

// ---------------- K5: per-row blocked-chain resolution w/ exact fallback ----------------
__global__ __launch_bounds__(256) void k_select(const int* __restrict__ cand_i,
                                                const float* __restrict__ sc_x,
                                                const unsigned* __restrict__ keys,
                                                int* __restrict__ idx_all) {
  int b = blockIdx.x, t = threadIdx.x;
  __shared__ unsigned mask[128];
  __shared__ int pick_s;
  __shared__ float ls_v[4];
  __shared__ int   ls_i[4];
  if (t < 128) mask[t] = 0u;
  __syncthreads();
  for (int j = 0; j < MAXR; j++) {
    if (t == 0) {
      const int* ci = &cand_i[(size_t)(b*MAXR + j) * NCAND];
      int pick = -1;
      #pragma unroll
      for (int r = 0; r < NCAND; r++) {
        int idx = ci[r];
        if (pick < 0 && !((mask[idx >> 5] >> (idx & 31)) & 1u)) pick = idx;
      }
      pick_s = pick;
    }
    __syncthreads();
    if (pick_s < 0) {
      unsigned kk0 = keys[2*j], kk1 = keys[2*j+1];
      float lv = -INFINITY; int li = 0x7FFFFFFF;
      for (int p = 0; p < 16; p++) {
        int d = t + 256*p;
        if ((mask[d >> 5] >> (d & 31)) & 1u) continue;
        float vv = sc_x[(size_t)b*DD + d] + gumbel_of(kk0, kk1, (unsigned)(b*DD + d));
        if (vv > lv || (vv == lv && d < li)) { lv = vv; li = d; }
      }
      float bv = lv; int bi = li;
      #pragma unroll
      for (int off = 32; off > 0; off >>= 1) {
        float ov = __shfl_down(bv, off);
        int   oi = __shfl_down(bi, off);
        if (ov > bv || (ov == bv && oi < bi)) { bv = ov; bi = oi; }
      }
      if ((t & 63) == 0) { ls_v[t >> 6] = bv; ls_i[t >> 6] = bi; }
      __syncthreads();
      if (t == 0) {
        float fv = ls_v[0]; int fi = ls_i[0];
        #pragma unroll
        for (int w = 1; w < 4; w++)
          if (ls_v[w] > fv || (ls_v[w] == fv && ls_i[w] < fi)) { fv = ls_v[w]; fi = ls_i[w]; }
        pick_s = fi;
      }
      __syncthreads();
    }
    if (t == 0) {
      int pk = pick_s;
      idx_all[b*MAXR + j] = pk;
      mask[pk >> 5] |= (1u << (pk & 31));
    }
    __syncthreads();
  }
}

// ---------------- K6: y, grad_y (incremental), sc_y, score_y ----------------
__global__ __launch_bounds__(256) void k_y(const float* __restrict__ x, const float* __restrict__ W,
    const float* __restrict__ bias, const float* __restrict__ grad_x,
    const int* __restrict__ idx_all, const int* __restrict__ radius,
    float* __restrict__ yv, float* __restrict__ sc_y, double* __restrict__ score_y) {
  int b = blockIdx.x, t = threadIdx.x;
  __shared__ int   fidx[MAXR];
  __shared__ float fsgn[MAXR];
  int nf = radius[b];
  if (t < nf) {
    int id = idx_all[b*MAXR + t];
    fidx[t] = id;
    fsgn[t] = 1.0f - 2.0f * x[(size_t)b*DD + id];
  }
  __syncthreads();
  double s1 = 0.0, s2 = 0.0;
  for (int k = 0; k < 16; k++) {
    int d = t + 256*k;
    size_t o = (size_t)b*DD + d;
    float g = grad_x[o];
    float xval = x[o];
    float yval = xval;
    for (int jj = 0; jj < nf; jj++) {
      g = fmaf(fsgn[jj], W[(size_t)fidx[jj]*DD + d], g);
      if (fidx[jj] == d) yval = 1.0f - xval;
    }
    yv[o] = yval;
    sc_y[o] = (1.0f - 2.0f*yval) * g * 0.5f;
    s1 += (double)yval * (double)g;
    s2 += (double)yval * (double)bias[d];
  }
  __shared__ double lds[4];
  double S1 = blockReduce256(s1, lds);
  double S2 = blockReduce256(s2, lds);
  if (t == 0) score_y[b] = 0.5 * (S1 + S2);
}

// ---------------- K7: masked log-softmax sums, accept, output ----------------
__global__ __launch_bounds__(256) void k_accept(const float* __restrict__ x, const float* __restrict__ yv,
    const float* __restrict__ sc_x, const float* __restrict__ sc_y,
    const int* __restrict__ idx_all, const int* __restrict__ radius,
    const double* __restrict__ score_x, const double* __restrict__ score_y,
    const float* __restrict__ u_acc, float* __restrict__ out) {
  int b = blockIdx.x, t = threadIdx.x;
  double sx = 0.0, sy = 0.0;
  for (int k = 0; k < 16; k++) {
    int d = t + 256*k; size_t o = (size_t)b*DD + d;
    sx += exp((double)sc_x[o]);
    sy += exp((double)sc_y[o]);
  }
  __shared__ double lds[4];
  double S = blockReduce256(sx, lds);
  double T = blockReduce256(sy, lds);
  __shared__ float accf;
  if (t == 0) {
    int nf = radius[b];
    const int* ia = &idx_all[b*MAXR];
    double lf = 0.0, pre = 0.0;
    for (int jj = 0; jj < MAXR; jj++) {
      int id = ia[jj];
      double scv = (double)sc_x[(size_t)b*DD + id];
      if (jj < nf) lf += scv - dlog(S - pre);
      pre += exp(scv);
    }
    double lb = 0.0, suf = 0.0;
    for (int jj = MAXR-1; jj >= 0; jj--) {
      int id = ia[jj];
      double scv = (double)sc_y[(size_t)b*DD + id];
      if (jj < nf) lb += scv - dlog(T - suf);
      suf += exp(scv);
    }
    double log_acc = (lb + score_y[b]) - (lf + score_x[b]);
    accf = (exp(log_acc) >= (double)u_acc[b]) ? 1.0f : 0.0f;
  }
  __syncthreads();
  float a = accf;
  for (int k = 0; k < 16; k++) {
    int d = t + 256*k; size_t o = (size_t)b*DD + d;
    out[o] = a * yv[o] + (1.0f - a) * x[o];
  }
}

extern "C" void kernel_launch(void* const* d_in, const int* in_sizes, int n_in,
                              void* d_out, int out_size, void* d_ws, size_t ws_size,
                              hipStream_t stream) {
  const float* x    = (const float*)d_in[0];
  const float* W    = (const float*)d_in[1];
  const float* bias = (const float*)d_in[2];
  float* out = (float*)d_out;
  char* ws = (char*)d_ws;
  const size_t MB = 1ull << 20;

  float*          grad_x  = (float*)         (ws + 0*MB);
  float*          sc_x    = (float*)         (ws + 4*MB);
  float*          sc_y    = (float*)         (ws + 8*MB);
  float*          yv      = (float*)         (ws + 12*MB);
  unsigned short* xb      = (unsigned short*)(ws + 16*MB);
  int*            cand_i  = (int*)           (ws + 20*MB);
  int*            idx_all = (int*)           (ws + 21*MB);
  int*            radius  = (int*)           (ws + 21*MB + 64*1024);
  float*          u_acc   = (float*)         (ws + 21*MB + 68*1024);
  unsigned*       keys    = (unsigned*)      (ws + 21*MB + 72*1024);
  double*         score_x = (double*)        (ws + 21*MB + 80*1024);
  double*         score_y = (double*)        (ws + 21*MB + 96*1024);
  float*          scmax   = (float*)         (ws + 21*MB + 112*1024);
  float*          Cpart   = (float*)         (ws + 22*MB);

  size_t base = 22*MB;
  int KC = 1;
  if      (ws_size >= base + 32*MB) KC = 8;
  else if (ws_size >= base + 16*MB) KC = 4;
  else if (ws_size >= base +  8*MB) KC = 2;

  k_rng      <<<1, 256, 0, stream>>>(keys, radius, u_acc);
  k_xcvt     <<<512, 256, 0, stream>>>(x, xb);
  k_gemm_mfma<<<dim3(DD/64, 2, KC), 256, 0, stream>>>(xb, W, Cpart, DD/KC);
  k_reduce   <<<dim3(DD/64, BB/64), 256, 0, stream>>>(Cpart, bias, x, grad_x, sc_x, KC);
  k_score    <<<BB, 256, 0, stream>>>(x, grad_x, bias, score_x, scmax);
  k_cand     <<<BB*MAXR, 256, 0, stream>>>(sc_x, keys, scmax, cand_i);
  k_select   <<<BB, 256, 0, stream>>>(cand_i, sc_x, keys, idx_all);
  k_y        <<<BB, 256, 0, stream>>>(x, W, bias, grad_x, idx_all, radius, yv, sc_y, score_y);
  k_accept   <<<BB, 256, 0, stream>>>(x, yv, sc_x, sc_y, idx_all, radius, score_x, score_y, u_acc, out);
}